// Round 2
// baseline (77.784 us; speedup 1.0000x reference)
//
#include <hip/hip_runtime.h>
#include <stdint.h>

#define N_ 8192
#define D_ 64
#define M_ 3
#define ROWS 16        // output rows per block (one MFMA row-tile)
#define XR (ROWS + 4)  // X rows staged: r0 .. r0+18 (+1 spare) = 20
#define WC (ROWS + 4)  // Wf cols staged: r0 .. r0+18 (+1 spare) = 20
#define PAD 68         // LDS inner pad (floats): 68%32=4 -> ~2-way max aliasing, 16B-aligned rows

typedef __attribute__((ext_vector_type(8))) short short8;
typedef __attribute__((ext_vector_type(8))) __bf16 bf16x8;
typedef __attribute__((ext_vector_type(4))) float f32x4;

// float -> bf16 (round-to-nearest-even) on raw bits
__device__ __forceinline__ short f2bf(float f) {
    uint32_t u = __builtin_bit_cast(uint32_t, f);
    u = (u + 0x7FFFu + ((u >> 16) & 1u)) >> 16;
    return (short)(u & 0xFFFFu);
}

__device__ __forceinline__ f32x4 mfma16(short8 a, short8 b, f32x4 c) {
    return __builtin_amdgcn_mfma_f32_16x16x32_bf16(
        __builtin_bit_cast(bf16x8, a), __builtin_bit_cast(bf16x8, b), c, 0, 0, 0);
}

__global__ __launch_bounds__(256, 4) void smf_kernel(
    const float* __restrict__ X,    // [B][N][64]
    const float* __restrict__ Wg,   // [64][64]
    const float* __restrict__ bg,   // [64]
    const float* __restrict__ Wf,   // [3][64][N]
    const float* __restrict__ bfv,  // [3][N]
    float* __restrict__ Out)        // [B][N][64]
{
    __shared__ __align__(16) float Wfs[M_][WC][PAD];  // transposed: [m][col][d], 16320 B
    __shared__ __align__(16) float Xs[XR][PAD];       // 5440 B
    __shared__ float pd[M_][ROWS + 2][4];             // partial d-dots (k quarters)
    __shared__ float po[M_][ROWS + 2][4];             // partial o-dots
    __shared__ float cks[5][ROWS];                    // c0..c3, csum

    const int tid = threadIdx.x;
    const int bid = blockIdx.x;
    const int b   = bid & 1;             // adjacent blocks share the Wf/X chunk (L2 reuse)
    const int r0  = (bid >> 1) * ROWS;
    const float* Xb = X + (size_t)b * N_ * D_;

    const int w  = tid >> 6;   // wave id = output col-tile te
    const int l  = tid & 63;
    const int lo = l & 15;
    const int q  = l >> 4;

    // ---- early: B fragments (Wg, bf16) for this wave's col-tile; pure global, overlaps staging ----
    short8 Bfrag[2];
    #pragma unroll
    for (int kh = 0; kh < 2; ++kh) {
        short8 s;
        #pragma unroll
        for (int jj = 0; jj < 8; ++jj) {
            int k = kh * 32 + q * 8 + jj;            // B[k][n], n = lane&15
            s[jj] = f2bf(Wg[k * 64 + w * 16 + lo]);
        }
        Bfrag[kh] = s;
    }
    const float bgv = bg[w * 16 + lo];

    // ---- stage X rows r0..r0+19 (coalesced f32x4) ----
    for (int p = tid; p < XR * 16; p += 256) {
        int rr = p >> 4, c4 = p & 15;
        int row = (r0 + rr) & (N_ - 1);
        f32x4 v = *(const f32x4*)(Xb + (size_t)row * D_ + c4 * 4);
        *(f32x4*)&Xs[rr][c4 * 4] = v;
    }
    // ---- stage Wf cols r0..r0+19, transposed into Wfs[m][col][d] ----
    for (int p = tid; p < M_ * D_ * 5; p += 256) {
        int m = p / (D_ * 5), rem = p - m * (D_ * 5);
        int d = rem / 5, c4 = rem - d * 5;
        int col = (r0 + c4 * 4) & (N_ - 1);          // r0 16-aligned: group never splits
        f32x4 v = *(const f32x4*)(Wf + ((size_t)(m * D_ + d)) * N_ + col);
        Wfs[m][c4 * 4 + 0][d] = v[0];
        Wfs[m][c4 * 4 + 1][d] = v[1];
        Wfs[m][c4 * 4 + 2][d] = v[2];
        Wfs[m][c4 * 4 + 3][d] = v[3];
    }
    __syncthreads();

    // ---- phase 1: partial d/o dots, 4 k-quarters per (m,j); 216 threads ----
    if (tid < M_ * (ROWS + 2) * 4) {
        int m = tid / ((ROWS + 2) * 4);
        int rem = tid - m * ((ROWS + 2) * 4);
        int j = rem >> 2, part = rem & 3;
        int k0 = part * 16;
        float ad = 0.f, ao = 0.f;
        #pragma unroll
        for (int g = 0; g < 4; ++g) {
            f32x4 xv = *(const f32x4*)&Xs[j][k0 + 4 * g];
            f32x4 wd = *(const f32x4*)&Wfs[m][j][k0 + 4 * g];
            f32x4 wo = *(const f32x4*)&Wfs[m][j + 1][k0 + 4 * g];
            #pragma unroll
            for (int t = 0; t < 4; ++t) { ad += xv[t] * wd[t]; ao += xv[t] * wo[t]; }
        }
        if (part == 0) {
            int gi  = (r0 + j) & (N_ - 1);
            int gi1 = (gi + 1) & (N_ - 1);
            ad += bfv[m * N_ + gi];
            ao += bfv[m * N_ + gi1];
        }
        pd[m][j][part] = ad;
        po[m][j][part] = ao;
    }
    __syncthreads();

    // ---- phase 2: reduce quarters + path-product chain coefficients; 16 threads ----
    if (tid < ROWS) {
        int j = tid;
#define RS(arr, m, jj) (arr[m][jj][0] + arr[m][jj][1] + arr[m][jj][2] + arr[m][jj][3])
        float D0  = RS(pd, 0, j),     O0  = RS(po, 0, j);
        float D0p = RS(pd, 0, j + 1), O0p = RS(po, 0, j + 1);
        float D0q = RS(pd, 0, j + 2), O0q = RS(po, 0, j + 2);
        float D1  = RS(pd, 1, j),     O1  = RS(po, 1, j);
        float D1p = RS(pd, 1, j + 1), O1p = RS(po, 1, j + 1);
        float D2  = RS(pd, 2, j),     O2  = RS(po, 2, j);
#undef RS
        float c0 = D2 * D1 * D0;
        float c1 = D2 * D1 * O0 + D2 * O1 * D0p + O2 * D1p * D0p;
        float c2 = D2 * O1 * O0p + O2 * D1p * O0p + O2 * O1p * D0q;
        float c3 = O2 * O1p * O0q;
        cks[0][j] = c0; cks[1][j] = c1; cks[2][j] = c2; cks[3][j] = c3;
        cks[4][j] = c0 + c1 + c2 + c3;
    }
    __syncthreads();

    // ---- phase 3: Y = sum_k c_k * X[i+k] in A-frag layout -> MFMA -> epilogue ----
    float ck[4];
    #pragma unroll
    for (int k = 0; k < 4; ++k) ck[k] = cks[k][lo];   // A-frag row m = lane&15

    f32x4 acc = (f32x4){0.f, 0.f, 0.f, 0.f};
    #pragma unroll
    for (int kh = 0; kh < 2; ++kh) {
        int cbase = kh * 32 + q * 8;
        f32x4 ya = (f32x4){0.f, 0.f, 0.f, 0.f};
        f32x4 yb = (f32x4){0.f, 0.f, 0.f, 0.f};
        #pragma unroll
        for (int k = 0; k < 4; ++k) {
            f32x4 xa = *(const f32x4*)&Xs[lo + k][cbase];
            f32x4 xb = *(const f32x4*)&Xs[lo + k][cbase + 4];
            #pragma unroll
            for (int t = 0; t < 4; ++t) { ya[t] += ck[k] * xa[t]; yb[t] += ck[k] * xb[t]; }
        }
        short8 A;
        #pragma unroll
        for (int jj = 0; jj < 4; ++jj) { A[jj] = f2bf(ya[jj]); A[4 + jj] = f2bf(yb[jj]); }
        acc = mfma16(A, Bfrag[kh], acc);
    }

    // C/D layout: col = lane&15, row = (lane>>4)*4 + reg
    #pragma unroll
    for (int r = 0; r < 4; ++r) {
        int orow = q * 4 + r;
        float v = acc[r] + cks[4][orow] * bgv;
        Out[((size_t)b * N_ + (r0 + orow)) * D_ + w * 16 + lo] = v;
    }
}

extern "C" void kernel_launch(void* const* d_in, const int* in_sizes, int n_in,
                              void* d_out, int out_size, void* d_ws, size_t ws_size,
                              hipStream_t stream) {
    const float* X   = (const float*)d_in[0];
    const float* Wg  = (const float*)d_in[1];
    const float* bg  = (const float*)d_in[2];
    const float* Wf  = (const float*)d_in[3];
    const float* bfv = (const float*)d_in[4];
    float* Out = (float*)d_out;

    dim3 grid(2 * (N_ / ROWS));   // 1024 blocks: (chunk, b) with b = bid&1 -> 4 blocks/CU
    dim3 block(256);
    hipLaunchKernelGGL(smf_kernel, grid, block, 0, stream, X, Wg, bg, Wf, bfv, Out);
}

// Round 3
// 76.575 us; speedup vs baseline: 1.0158x; 1.0158x over previous
//
#include <hip/hip_runtime.h>
#include <stdint.h>

#define N_ 8192
#define D_ 64
#define M_ 3
#define ROWS 16        // output rows per block (one MFMA row-tile)
#define SR (ROWS + 4)  // staged X rows / Wf cols: r0..r0+18 used, 20 staged
#define PAD 68         // LDS inner pad (floats): stride%32==4 -> 2-way max (free), 16B aligned

typedef __attribute__((ext_vector_type(8))) short short8;
typedef __attribute__((ext_vector_type(8))) __bf16 bf16x8;
typedef __attribute__((ext_vector_type(4))) float f32x4;

// float -> bf16 (round-to-nearest-even) on raw bits
__device__ __forceinline__ short f2bf(float f) {
    uint32_t u = __builtin_bit_cast(uint32_t, f);
    u = (u + 0x7FFFu + ((u >> 16) & 1u)) >> 16;
    return (short)(u & 0xFFFFu);
}

__device__ __forceinline__ f32x4 mfma16(short8 a, short8 b, f32x4 c) {
    return __builtin_amdgcn_mfma_f32_16x16x32_bf16(
        __builtin_bit_cast(bf16x8, a), __builtin_bit_cast(bf16x8, b), c, 0, 0, 0);
}

__global__ __launch_bounds__(256, 4) void smf_kernel(
    const float* __restrict__ X,    // [B][N][64]
    const float* __restrict__ Wg,   // [64][64]
    const float* __restrict__ bg,   // [64]
    const float* __restrict__ Wf,   // [3][64][N]
    const float* __restrict__ bfv,  // [3][N]
    float* __restrict__ Out)        // [B][N][64]
{
    __shared__ __align__(16) float Wfs[M_][SR][PAD];  // transposed: [m][col][d]
    __shared__ __align__(16) float Xs[SR][PAD];
    __shared__ float dd[M_][ROWS + 2];                // full d-dots
    __shared__ float oo[M_][ROWS + 2];                // full o-dots

    const int tid = threadIdx.x;
    const int bid = blockIdx.x;
    const int b   = bid & 1;
    const int r0  = (bid >> 1) * ROWS;
    const float* Xb = X + (size_t)b * N_ * D_;

    const int w  = tid >> 6;   // wave id = output col-tile
    const int l  = tid & 63;
    const int lo = l & 15;
    const int q  = l >> 4;

    // ---- prefetch bfv for dot threads (pure global, pre-barrier) ----
    const bool dotActive = (tid < M_ * (ROWS + 2));   // 54 threads
    int m1 = 0, j1 = 0;
    float pbd = 0.f, pbo = 0.f;
    if (dotActive) {
        m1 = tid / (ROWS + 2);
        j1 = tid - m1 * (ROWS + 2);
        int gi  = (r0 + j1) & (N_ - 1);
        int gi1 = (gi + 1) & (N_ - 1);
        pbd = bfv[m1 * N_ + gi];
        pbo = bfv[m1 * N_ + gi1];
    }

    // ---- stage X rows r0..r0+19 (coalesced f32x4) ----
    for (int p = tid; p < SR * 16; p += 256) {
        int rr = p >> 4, c4 = p & 15;
        int row = (r0 + rr) & (N_ - 1);
        f32x4 v = *(const f32x4*)(Xb + (size_t)row * D_ + c4 * 4);
        *(f32x4*)&Xs[rr][c4 * 4] = v;
    }
    // ---- stage Wf cols r0..r0+19, transposed into Wfs[m][col][d] ----
    for (int p = tid; p < M_ * D_ * 5; p += 256) {
        int m = p / (D_ * 5), rem = p - m * (D_ * 5);
        int d = rem / 5, c4 = rem - d * 5;
        int col = (r0 + c4 * 4) & (N_ - 1);          // 4-aligned: never splits across wrap
        f32x4 v = *(const f32x4*)(Wf + ((size_t)(m * D_ + d)) * N_ + col);
        Wfs[m][c4 * 4 + 0][d] = v[0];
        Wfs[m][c4 * 4 + 1][d] = v[1];
        Wfs[m][c4 * 4 + 2][d] = v[2];
        Wfs[m][c4 * 4 + 3][d] = v[3];
    }

    // ---- B fragments (Wg) + bg: global loads overlapping the staging latency ----
    short8 Bfrag[2];
    #pragma unroll
    for (int kh = 0; kh < 2; ++kh) {
        short8 s;
        #pragma unroll
        for (int jj = 0; jj < 8; ++jj) {
            int k = kh * 32 + q * 8 + jj;            // B[k][n], n = lane&15
            s[jj] = f2bf(Wg[k * 64 + w * 16 + lo]);
        }
        Bfrag[kh] = s;
    }
    const float bgv = bg[w * 16 + lo];

    __syncthreads();   // barrier 1: staging complete

    // ---- phase 1: full 64-length d/o dots, 54 threads, vectorized LDS ----
    if (dotActive) {
        float ad = pbd, ao = pbo;
        #pragma unroll
        for (int g = 0; g < 16; ++g) {
            f32x4 xv = *(const f32x4*)&Xs[j1][4 * g];
            f32x4 wd = *(const f32x4*)&Wfs[m1][j1][4 * g];
            f32x4 wo = *(const f32x4*)&Wfs[m1][j1 + 1][4 * g];
            #pragma unroll
            for (int t = 0; t < 4; ++t) { ad += xv[t] * wd[t]; ao += xv[t] * wo[t]; }
        }
        dd[m1][j1] = ad;
        oo[m1][j1] = ao;
    }
    __syncthreads();   // barrier 2: dots visible

    // ---- per-lane chain coefficients for row lo (broadcast LDS reads, redundant) ----
    float D0  = dd[0][lo],     O0  = oo[0][lo];
    float D0p = dd[0][lo + 1], O0p = oo[0][lo + 1];
    float D0q = dd[0][lo + 2], O0q = oo[0][lo + 2];
    float D1  = dd[1][lo],     O1  = oo[1][lo];
    float D1p = dd[1][lo + 1], O1p = oo[1][lo + 1];
    float D2  = dd[2][lo],     O2  = oo[2][lo];
    float ck0 = D2 * D1 * D0;
    float ck1 = D2 * D1 * O0 + D2 * O1 * D0p + O2 * D1p * D0p;
    float ck2 = D2 * O1 * O0p + O2 * D1p * O0p + O2 * O1p * D0q;
    float ck3 = O2 * O1p * O0q;
    float csum = ck0 + ck1 + ck2 + ck3;
    float ck[4] = {ck0, ck1, ck2, ck3};

    // ---- phase 3: Y = sum_k c_k * X[i+k] in A-frag layout -> MFMA ----
    f32x4 acc = (f32x4){0.f, 0.f, 0.f, 0.f};
    #pragma unroll
    for (int kh = 0; kh < 2; ++kh) {
        int cbase = kh * 32 + q * 8;
        f32x4 ya = (f32x4){0.f, 0.f, 0.f, 0.f};
        f32x4 yb = (f32x4){0.f, 0.f, 0.f, 0.f};
        #pragma unroll
        for (int k = 0; k < 4; ++k) {
            f32x4 xa = *(const f32x4*)&Xs[lo + k][cbase];
            f32x4 xb = *(const f32x4*)&Xs[lo + k][cbase + 4];
            #pragma unroll
            for (int t = 0; t < 4; ++t) { ya[t] += ck[k] * xa[t]; yb[t] += ck[k] * xb[t]; }
        }
        short8 A;
        #pragma unroll
        for (int jj = 0; jj < 4; ++jj) { A[jj] = f2bf(ya[jj]); A[4 + jj] = f2bf(yb[jj]); }
        acc = mfma16(A, Bfrag[kh], acc);
    }

    // ---- epilogue: C/D layout col=lane&15, row=q*4+r; csum via shuffle (lane orow holds it) ----
    #pragma unroll
    for (int r = 0; r < 4; ++r) {
        int orow = q * 4 + r;
        float cs = __shfl(csum, orow);
        float v = acc[r] + cs * bgv;
        Out[((size_t)b * N_ + (r0 + orow)) * D_ + w * 16 + lo] = v;
    }
}

extern "C" void kernel_launch(void* const* d_in, const int* in_sizes, int n_in,
                              void* d_out, int out_size, void* d_ws, size_t ws_size,
                              hipStream_t stream) {
    const float* X   = (const float*)d_in[0];
    const float* Wg  = (const float*)d_in[1];
    const float* bg  = (const float*)d_in[2];
    const float* Wf  = (const float*)d_in[3];
    const float* bfv = (const float*)d_in[4];
    float* Out = (float*)d_out;

    dim3 grid(2 * (N_ / ROWS));   // 1024 blocks -> 4 blocks/CU
    dim3 block(256);
    hipLaunchKernelGGL(smf_kernel, grid, block, 0, stream, X, Wg, bg, Wf, bfv, Out);
}